// Round 1
// baseline (249.978 us; speedup 1.0000x reference)
//
#include <hip/hip_runtime.h>

// Problem constants (fixed by the reference): x is (B, C, D, H, W) float32,
// output is (B, D, H, W) float32 = log(det(I + grad(u)))^2 per voxel.
constexpr int B = 2, C = 3, D = 128, H = 192, W = 192;
constexpr int sH = W;          // stride of h in elements
constexpr int sD = H * W;      // stride of d
constexpr int sC = D * H * W;  // stride of c
constexpr long sB = (long)C * sC;

// One block per (b,d,h) row; threadIdx.x = w (192 threads = 3 waves).
// J[j][i] = d(u_i)/d(x_j) + delta_ij with numpy-style gradient
// (central diff interior, one-sided at boundaries), then log(det)^2.
__global__ __launch_bounds__(192) void jac_logdet_sq(
    const float* __restrict__ x, float* __restrict__ out) {
    const int w = threadIdx.x;
    int rid = blockIdx.x;          // rid = (b*D + d)*H + h
    const int h = rid % H;
    rid /= H;
    const int d = rid % D;
    const int b = rid / D;

    const long base = (long)b * sB + (long)d * sD + (long)h * sH + w;

    float J[3][3];
#pragma unroll
    for (int c = 0; c < 3; ++c) {
        const float* p = x + base + (long)c * sC;

        float gw, gh, gd;
        // gradient along W (axis 2 of spatial -> row j=2)
        if (w == 0)          gw = p[1] - p[0];
        else if (w == W - 1) gw = p[0] - p[-1];
        else                 gw = 0.5f * (p[1] - p[-1]);
        // gradient along H (row j=1)
        if (h == 0)          gh = p[sH] - p[0];
        else if (h == H - 1) gh = p[0] - p[-sH];
        else                 gh = 0.5f * (p[sH] - p[-sH]);
        // gradient along D (row j=0)
        if (d == 0)          gd = p[sD] - p[0];
        else if (d == D - 1) gd = p[0] - p[-sD];
        else                 gd = 0.5f * (p[sD] - p[-sD]);

        J[0][c] = gd + (c == 0 ? 1.0f : 0.0f);
        J[1][c] = gh + (c == 1 ? 1.0f : 0.0f);
        J[2][c] = gw + (c == 2 ? 1.0f : 0.0f);
    }

    const float det =
          J[0][0] * (J[1][1] * J[2][2] - J[1][2] * J[2][1])
        - J[0][1] * (J[1][0] * J[2][2] - J[1][2] * J[2][0])
        + J[0][2] * (J[1][0] * J[2][1] - J[1][1] * J[2][0]);

    const float l = logf(det);   // det > 0 by construction (small displacements)
    // out index = ((b*D + d)*H + h)*W + w = blockIdx.x*W + w
    out[(long)blockIdx.x * W + w] = l * l;
}

extern "C" void kernel_launch(void* const* d_in, const int* in_sizes, int n_in,
                              void* d_out, int out_size, void* d_ws, size_t ws_size,
                              hipStream_t stream) {
    const float* x = (const float*)d_in[0];
    float* out = (float*)d_out;
    jac_logdet_sq<<<dim3(B * D * H), dim3(W), 0, stream>>>(x, out);
}

// Round 2
// 180.650 us; speedup vs baseline: 1.3838x; 1.3838x over previous
//
#include <hip/hip_runtime.h>

// x: (B, C, D, H, W) float32; out: (B, D, H, W) float32 = log(det(I+grad u))^2.
constexpr int B = 2, C = 3, D = 128, H = 192, W = 192;
constexpr int sH = W;          // stride of h (elements)
constexpr int sD = H * W;      // stride of d
constexpr int sC = D * H * W;  // stride of c
constexpr int sB = C * sC;     // stride of b (28.3M elems — fits int32)
constexpr int W4 = W / 4;      // 48 float4-groups per row
constexpr int NG = B * D * H * W4;  // 2,359,296 thread-groups; /256 = 9216 blocks exact

// Each thread computes 4 consecutive w-voxels from float4 loads.
// vmem per thread: 3 ch x (5 float4 + 2 scalar) loads + 1 float4 store.
__global__ __launch_bounds__(256) void jac_logdet_sq(
    const float* __restrict__ x, float* __restrict__ out) {
    const int g = blockIdx.x * 256 + threadIdx.x;   // group id, flat
    const int w4 = g % W4;
    int rid = g / W4;
    const int h = rid % H;
    rid /= H;
    const int d = rid % D;
    const int b = rid / D;
    const int w0 = w4 * 4;

    const int base = b * sB + d * sD + h * sH + w0;  // 16B-aligned (w0 % 4 == 0)

    float gd[3][4], gh[3][4], gw[3][4];

    const int offL = (w0 > 0) ? -1 : 0;          // clamped W-edge taps
    const int offR = (w0 + 4 < W) ? 4 : 3;
    const int offHp = (h < H - 1) ? sH : 0;      // clamped H/D taps: one-sided
    const int offHm = (h > 0) ? sH : 0;          //  boundaries fall out of the
    const int offDp = (d < D - 1) ? sD : 0;      //  coeff select below
    const int offDm = (d > 0) ? sD : 0;
    const float ch = (h > 0 && h < H - 1) ? 0.5f : 1.0f;
    const float cd = (d > 0 && d < D - 1) ? 0.5f : 1.0f;

#pragma unroll
    for (int c = 0; c < 3; ++c) {
        const float* p = x + base + c * sC;
        const float4 vm  = *(const float4*)p;
        const float  lft = p[offL];
        const float  rgt = p[offR];
        const float4 vhp = *(const float4*)(p + offHp);
        const float4 vhm = *(const float4*)(p - offHm);
        const float4 vdp = *(const float4*)(p + offDp);
        const float4 vdm = *(const float4*)(p - offDm);

        gh[c][0] = (vhp.x - vhm.x) * ch;
        gh[c][1] = (vhp.y - vhm.y) * ch;
        gh[c][2] = (vhp.z - vhm.z) * ch;
        gh[c][3] = (vhp.w - vhm.w) * ch;

        gd[c][0] = (vdp.x - vdm.x) * cd;
        gd[c][1] = (vdp.y - vdm.y) * cd;
        gd[c][2] = (vdp.z - vdm.z) * cd;
        gd[c][3] = (vdp.w - vdm.w) * cd;

        // W gradient: interior central diffs from the register float4.
        gw[c][0] = (w0 == 0)     ? (vm.y - vm.x) : 0.5f * (vm.y - lft);
        gw[c][1] = 0.5f * (vm.z - vm.x);
        gw[c][2] = 0.5f * (vm.w - vm.y);
        gw[c][3] = (w0 + 4 == W) ? (vm.w - vm.z) : 0.5f * (rgt - vm.z);
    }

    float r[4];
#pragma unroll
    for (int e = 0; e < 4; ++e) {
        // J[j][i]: row j = d/dx_j (D,H,W), col i = channel; det transpose-inv.
        const float a00 = gd[0][e] + 1.0f, a01 = gd[1][e], a02 = gd[2][e];
        const float a10 = gh[0][e], a11 = gh[1][e] + 1.0f, a12 = gh[2][e];
        const float a20 = gw[0][e], a21 = gw[1][e], a22 = gw[2][e] + 1.0f;
        const float det = a00 * (a11 * a22 - a12 * a21)
                        - a01 * (a10 * a22 - a12 * a20)
                        + a02 * (a10 * a21 - a11 * a20);
        const float l = logf(det);
        r[e] = l * l;
    }

    *(float4*)(out + (long)g * 4) = make_float4(r[0], r[1], r[2], r[3]);
}

extern "C" void kernel_launch(void* const* d_in, const int* in_sizes, int n_in,
                              void* d_out, int out_size, void* d_ws, size_t ws_size,
                              hipStream_t stream) {
    const float* x = (const float*)d_in[0];
    float* out = (float*)d_out;
    jac_logdet_sq<<<dim3(NG / 256), dim3(256), 0, stream>>>(x, out);
}